// Round 2
// baseline (596.148 us; speedup 1.0000x reference)
//
#include <hip/hip_runtime.h>
#include <hip/hip_bf16.h>
#include <stdint.h>

#define Bn 32
#define Tn 2048
#define Hn 1024
#define Cn 1024

typedef short short8 __attribute__((ext_vector_type(8)));
typedef float floatx4 __attribute__((ext_vector_type(4)));

__device__ __forceinline__ unsigned int bf16_rne(float f) {
    union { float f; unsigned int u; } v; v.f = f;
    unsigned int u = v.u;
    return (u + 0x7fffu + ((u >> 16) & 1u)) >> 16;
}

// dbias[b][c] = sum_h dec[b][h]*W[h][c]  (+ bias[c] once)
// grid (32, 4, 4) x 256 threads; dbias must be zeroed first.
__global__ void k_dbias(const float* __restrict__ dec, const float* __restrict__ W,
                        const float* __restrict__ bias, float* __restrict__ dbias) {
    const int b  = blockIdx.x;
    const int c  = blockIdx.y * 256 + threadIdx.x;
    const int h0 = blockIdx.z * 256;
    const float* dv = dec + b * Hn + h0;
    const float* wp = W + (size_t)h0 * Cn + c;
    float acc = 0.f;
#pragma unroll 8
    for (int h = 0; h < 256; ++h)
        acc += dv[h] * wp[(size_t)h * Cn];
    if (blockIdx.z == 0) acc += bias[c];
    atomicAdd(&dbias[b * Cn + c], acc);
}

// Pack V[k][c] fp32 -> bf16 in MFMA B-fragment order:
// vp[(nt*32 + kt)*64 + lane] holds 8 bf16: V[kt*32 + (lane>>4)*8 + j][nt*16 + (lane&15)]
// grid 2048 (= 64 nt * 32 kt) x 64 threads.
__global__ void k_vpack(const float* __restrict__ V, uint4* __restrict__ vp) {
    const int bid  = blockIdx.x;
    const int nt   = bid >> 5;
    const int kt   = bid & 31;
    const int lane = threadIdx.x;
    const int c    = nt * 16 + (lane & 15);
    const int k0   = kt * 32 + (lane >> 4) * 8;
    unsigned int h[8];
#pragma unroll
    for (int j = 0; j < 8; ++j)
        h[j] = bf16_rne(V[(size_t)(k0 + j) * Cn + c]);
    uint4 u;
    u.x = h[0] | (h[1] << 16);
    u.y = h[2] | (h[3] << 16);
    u.z = h[4] | (h[5] << 16);
    u.w = h[6] | (h[7] << 16);
    vp[(size_t)bid * 64 + lane] = u;
}

#define BLK_M 64
#define LDA   1032   // 1024 + 8 bf16 pad -> 2064B row stride

struct ScoresShared {
    unsigned short A[BLK_M * LDA];  // 132096 B
    float scores[BLK_M];
};

// Fused enc_proj GEMM + tanh + dot(w) -> scores[B*T]
// grid 1024 x 512 threads (8 waves). Wave computes 64 rows x 64 cols per N-iter (2 iters).
// v3: progressive K-chunked A-staging (4 chunks of 256 K-cols) — chunk c+1's
// global loads issue BEFORE chunk c's 8 MFMA steps and the convert+ds_write
// lands after (T14 async-STAGE split), so HBM latency hides under MFMA.
// Depth-1 register prefetch of the L2-resident packed-V fragments removes the
// per-kt dependency stall. Chunk loops kept ROLLED (uniform barriers, small
// code); only the 8 kt-steps within a chunk are unrolled.
__global__ __launch_bounds__(512, 2)
void k_scores(const float* __restrict__ enc, const uint4* __restrict__ vp,
              const float* __restrict__ dbias, const float* __restrict__ wv,
              float* __restrict__ scores_g) {
    __shared__ ScoresShared sh;
    const int wg   = blockIdx.x;
    const int tid  = threadIdx.x;
    const int lane = tid & 63;
    const int wave = tid >> 6;
    const int b    = wg >> 5;          // 32 WGs per batch row-block
    const int row0 = wg * BLK_M;
    const int lhi  = lane >> 4;        // 0..3
    const int llo  = lane & 15;

    if (tid < BLK_M) sh.scores[tid] = 0.f;

    const float4* ep = (const float4*)(enc + (size_t)row0 * Hn);

    // --- prologue: stage K-chunk 0 (64 rows x 256 cols), preload B-frags for s=0
    float4 f[8];
#pragma unroll
    for (int i = 0; i < 8; ++i) {
        int idx = tid + i * 512;                  // 0..4095
        f[i] = ep[(idx >> 6) * 256 + (idx & 63)]; // r = idx>>6, c4 = idx&63
    }
    uint4 bcur[4];
#pragma unroll
    for (int j = 0; j < 4; ++j)
        bcur[j] = vp[((wave * 4 + j) * 32 + 0) * 64 + lane];
#pragma unroll
    for (int i = 0; i < 8; ++i) {
        int idx = tid + i * 512;
        int r = idx >> 6, c4 = idx & 63;
        uint2 p;
        p.x = bf16_rne(f[i].x) | (bf16_rne(f[i].y) << 16);
        p.y = bf16_rne(f[i].z) | (bf16_rne(f[i].w) << 16);
        *(uint2*)&sh.A[r * LDA + c4 * 4] = p;
    }
    __syncthreads();

    float score_part[16];
#pragma unroll
    for (int i = 0; i < 16; ++i) score_part[i] = 0.f;

    floatx4 acc[4][4];
#pragma unroll
    for (int i = 0; i < 4; ++i)
#pragma unroll
        for (int j = 0; j < 4; ++j)
            acc[i][j] = (floatx4){0.f, 0.f, 0.f, 0.f};

    for (int ni = 0; ni < 2; ++ni) {
        for (int ck = 0; ck < 4; ++ck) {
            // Issue next chunk's global loads before this chunk's MFMA work
            // (first N-pass only; by ni=1 all of A is staged).
            if (ni == 0 && ck < 3) {
#pragma unroll
                for (int i = 0; i < 8; ++i) {
                    int idx = tid + i * 512;
                    f[i] = ep[(idx >> 6) * 256 + (ck + 1) * 64 + (idx & 63)];
                }
            }

#pragma unroll
            for (int k8 = 0; k8 < 8; ++k8) {
                const int kt = ck * 8 + k8;

                short8 afr[4];
#pragma unroll
                for (int rg = 0; rg < 4; ++rg)
                    afr[rg] = *(const short8*)&sh.A[(rg * 16 + llo) * LDA + kt * 32 + lhi * 8];

                // Depth-1 prefetch of next step's packed-V fragments (L2).
                uint4 bn[4];
                const bool haveNext = !(ni == 1 && kt == 31);
                if (haveNext) {
                    const int s1  = ni * 32 + kt + 1;
                    const int nt1 = ((s1 >> 5) * 8 + wave) * 4;
                    const int kt1 = s1 & 31;
#pragma unroll
                    for (int j = 0; j < 4; ++j)
                        bn[j] = vp[((nt1 + j) * 32 + kt1) * 64 + lane];
                }

#pragma unroll
                for (int rg = 0; rg < 4; ++rg)
#pragma unroll
                    for (int j = 0; j < 4; ++j)
                        acc[rg][j] = __builtin_amdgcn_mfma_f32_16x16x32_bf16(
                            afr[rg], __builtin_bit_cast(short8, bcur[j]), acc[rg][j], 0, 0, 0);

                if (haveNext) {
#pragma unroll
                    for (int j = 0; j < 4; ++j) bcur[j] = bn[j];
                }
            }

            // Convert + write the prefetched chunk, then one uniform barrier.
            if (ni == 0 && ck < 3) {
#pragma unroll
                for (int i = 0; i < 8; ++i) {
                    int idx = tid + i * 512;
                    int r = idx >> 6, c4 = idx & 63;
                    uint2 p;
                    p.x = bf16_rne(f[i].x) | (bf16_rne(f[i].y) << 16);
                    p.y = bf16_rne(f[i].z) | (bf16_rne(f[i].w) << 16);
                    *(uint2*)&sh.A[r * LDA + (ck + 1) * 256 + c4 * 4] = p;
                }
                __syncthreads();
            }
        }

        // Epilogue for this N-half: tanh + dot(w), reset accumulators.
        const int colbase = (ni * 8 + wave) * 64;
#pragma unroll
        for (int j = 0; j < 4; ++j) {
            const int c   = colbase + j * 16 + llo;
            const float db = dbias[b * Cn + c];
            const float wc = wv[c];
#pragma unroll
            for (int rg = 0; rg < 4; ++rg) {
#pragma unroll
                for (int r = 0; r < 4; ++r) {
                    float x = acc[rg][j][r] + db;
                    x = fminf(fmaxf(x, -12.f), 12.f);
                    float e = __expf(2.f * x);
                    float t = 1.f - 2.f / (e + 1.f);
                    score_part[rg * 4 + r] += t * wc;
                    acc[rg][j][r] = 0.f;
                }
            }
        }
    }

    // Reduce over the 16 lanes (llo) that share each row.
#pragma unroll
    for (int i = 0; i < 16; ++i) {
        float v = score_part[i];
        v += __shfl_xor(v, 1);
        v += __shfl_xor(v, 2);
        v += __shfl_xor(v, 4);
        v += __shfl_xor(v, 8);
        score_part[i] = v;
    }
    if (llo == 0) {
#pragma unroll
        for (int rg = 0; rg < 4; ++rg)
#pragma unroll
            for (int r = 0; r < 4; ++r)
                atomicAdd(&sh.scores[rg * 16 + lhi * 4 + r], score_part[rg * 4 + r]);
    }
    __syncthreads();
    if (tid < BLK_M) scores_g[row0 + tid] = sh.scores[tid];
}

// Softmax over T per batch. grid 32 x 256.
__global__ void k_softmax(const float* __restrict__ scores, float* __restrict__ align) {
    const int b   = blockIdx.x;
    const int tid = threadIdx.x;
    const float* s = scores + b * Tn;
    float v[8];
    float lmax = -1e30f;
#pragma unroll
    for (int i = 0; i < 8; ++i) { v[i] = s[tid + i * 256]; lmax = fmaxf(lmax, v[i]); }
    for (int off = 1; off < 64; off <<= 1) lmax = fmaxf(lmax, __shfl_xor(lmax, off));
    __shared__ float red[4];
    __shared__ float red2[4];
    if ((tid & 63) == 0) red[tid >> 6] = lmax;
    __syncthreads();
    lmax = fmaxf(fmaxf(red[0], red[1]), fmaxf(red[2], red[3]));
    float lsum = 0.f;
#pragma unroll
    for (int i = 0; i < 8; ++i) { v[i] = __expf(v[i] - lmax); lsum += v[i]; }
    for (int off = 1; off < 64; off <<= 1) lsum += __shfl_xor(lsum, off);
    if ((tid & 63) == 0) red2[tid >> 6] = lsum;
    __syncthreads();
    lsum = red2[0] + red2[1] + red2[2] + red2[3];
    const float inv = 1.f / lsum;
#pragma unroll
    for (int i = 0; i < 8; ++i) align[b * Tn + tid + i * 256] = v[i] * inv;
}

// context[b][h] = sum_t align[b][t] * enc[b][t][h]
// grid (32, 32 t-chunks) x 256 threads, float4 over full H; atomicAdd partials.
__global__ void k_context(const float* __restrict__ enc, const float* __restrict__ align,
                          float* __restrict__ out) {
    const int b   = blockIdx.x;
    const int tc  = blockIdx.y;
    const int tid = threadIdx.x;
    const float4* ep = (const float4*)(enc + ((size_t)b * Tn + tc * 64) * Hn);
    const float*  al = align + b * Tn + tc * 64;
    float4 acc = {0.f, 0.f, 0.f, 0.f};
#pragma unroll 4
    for (int t = 0; t < 64; ++t) {
        const float a = al[t];
        const float4 e = ep[t * 256 + tid];
        acc.x += a * e.x; acc.y += a * e.y; acc.z += a * e.z; acc.w += a * e.w;
    }
    float* op = out + b * Hn + tid * 4;
    atomicAdd(op + 0, acc.x);
    atomicAdd(op + 1, acc.y);
    atomicAdd(op + 2, acc.z);
    atomicAdd(op + 3, acc.w);
}

extern "C" void kernel_launch(void* const* d_in, const int* in_sizes, int n_in,
                              void* d_out, int out_size, void* d_ws, size_t ws_size,
                              hipStream_t stream) {
    const float* dec  = (const float*)d_in[0];   // [32,1,1024]
    const float* enc  = (const float*)d_in[1];   // [32,2048,1024]
    const float* W    = (const float*)d_in[2];   // [1024,1024]
    const float* V    = (const float*)d_in[3];   // [1024,1024]
    const float* bias = (const float*)d_in[4];   // [1024]
    const float* wv   = (const float*)d_in[5];   // [1024,1]
    float* out = (float*)d_out;                  // [32,1024]

    char* ws = (char*)d_ws;
    float* dbias  = (float*)(ws);                          // 128 KB
    uint4* vpack  = (uint4*)(ws + 131072);                 // 2 MB
    float* scores = (float*)(ws + 131072 + 2097152);       // 256 KB
    float* align  = (float*)(ws + 131072 + 2097152 + 262144); // 256 KB

    hipMemsetAsync(dbias, 0, 131072, stream);
    hipMemsetAsync(d_out, 0, Bn * Cn * sizeof(float), stream);

    k_dbias  <<<dim3(32, 4, 4), 256, 0, stream>>>(dec, W, bias, dbias);
    k_vpack  <<<2048, 64, 0, stream>>>(V, vpack);
    k_scores <<<1024, 512, 0, stream>>>(enc, vpack, dbias, wv, scores);
    k_softmax<<<32, 256, 0, stream>>>(scores, align);
    k_context<<<dim3(32, 32), 256, 0, stream>>>(enc, align, out);
}

// Round 4
// 570.412 us; speedup vs baseline: 1.0451x; 1.0451x over previous
//
#include <hip/hip_runtime.h>
#include <hip/hip_bf16.h>
#include <stdint.h>

#define Bn 32
#define Tn 2048
#define Hn 1024
#define Cn 1024

typedef short short8 __attribute__((ext_vector_type(8)));
typedef float floatx4 __attribute__((ext_vector_type(4)));

__device__ __forceinline__ unsigned int bf16_rne(float f) {
    union { float f; unsigned int u; } v; v.f = f;
    unsigned int u = v.u;
    return (u + 0x7fffu + ((u >> 16) & 1u)) >> 16;
}

// dbias partials: dbp[(b*4+z)][c] = sum_{h in z-chunk} dec[b][h]*W[h][c] (+ bias at z==0)
// grid (32, 4, 4) x 256 threads. Non-atomic plain stores; k_scores sums the 4 partials.
__global__ void k_dbias(const float* __restrict__ dec, const float* __restrict__ W,
                        const float* __restrict__ bias, float* __restrict__ dbp) {
    const int b  = blockIdx.x;
    const int c  = blockIdx.y * 256 + threadIdx.x;
    const int z  = blockIdx.z;
    const int h0 = z * 256;
    const float* dv = dec + b * Hn + h0;
    const float* wp = W + (size_t)h0 * Cn + c;
    float acc = 0.f;
#pragma unroll 8
    for (int h = 0; h < 256; ++h)
        acc += dv[h] * wp[(size_t)h * Cn];
    if (z == 0) acc += bias[c];
    dbp[(size_t)(b * 4 + z) * Cn + c] = acc;
}

// Pack V[k][c] fp32 -> bf16 in MFMA B-fragment order:
// vp[(nt*32 + kt)*64 + lane] holds 8 bf16: V[kt*32 + (lane>>4)*8 + j][nt*16 + (lane&15)]
// grid 2048 (= 64 nt * 32 kt) x 64 threads.
__global__ void k_vpack(const float* __restrict__ V, uint4* __restrict__ vp) {
    const int bid  = blockIdx.x;
    const int nt   = bid >> 5;
    const int kt   = bid & 31;
    const int lane = threadIdx.x;
    const int c    = nt * 16 + (lane & 15);
    const int k0   = kt * 32 + (lane >> 4) * 8;
    unsigned int h[8];
#pragma unroll
    for (int j = 0; j < 8; ++j)
        h[j] = bf16_rne(V[(size_t)(k0 + j) * Cn + c]);
    uint4 u;
    u.x = h[0] | (h[1] << 16);
    u.y = h[2] | (h[3] << 16);
    u.z = h[4] | (h[5] << 16);
    u.w = h[6] | (h[7] << 16);
    vp[(size_t)bid * 64 + lane] = u;
}

#define BLK_M 64
#define LDA   1032   // 1024 + 8 bf16 pad -> 2064B row stride, conflict-free ds_read_b128

struct ScoresShared {
    unsigned short A[BLK_M * LDA];  // 132096 B
    float scores[BLK_M];
};

// Fused enc_proj GEMM + tanh + dot(w) -> scores[B*T]
// grid 1024 x 512 threads (8 waves). Wave computes 64 rows x 64 cols per N-iter (2 iters).
// v4: exact v1 (248us-proven) structure; only change is summing the 4 dbias
// partials in the epilogue (L2-hot loads, replaces the atomics+memset path).
__global__ __launch_bounds__(512, 2)
void k_scores(const float* __restrict__ enc, const uint4* __restrict__ vp,
              const float* __restrict__ dbp, const float* __restrict__ wv,
              float* __restrict__ scores_g) {
    __shared__ ScoresShared sh;
    const int wg   = blockIdx.x;
    const int tid  = threadIdx.x;
    const int lane = tid & 63;
    const int wave = tid >> 6;
    const int b    = wg >> 5;          // 32 WGs per batch row-block
    const int row0 = wg * BLK_M;
    const int lhi  = lane >> 4;        // 0..3
    const int llo  = lane & 15;

    if (tid < BLK_M) sh.scores[tid] = 0.f;

    // Stage A (64 rows x 1024 fp32) -> bf16 LDS, coalesced float4 loads.
    {
        const float4* ep = (const float4*)(enc + (size_t)row0 * Hn);
#pragma unroll 4
        for (int it = 0; it < 32; ++it) {
            int idx = tid + it * 512;         // 0..16383
            int r   = idx >> 8;               // row 0..63
            int c4  = idx & 255;              // float4 index in row
            float4 f = ep[r * 256 + c4];
            uint2 p;
            p.x = bf16_rne(f.x) | (bf16_rne(f.y) << 16);
            p.y = bf16_rne(f.z) | (bf16_rne(f.w) << 16);
            *(uint2*)&sh.A[r * LDA + c4 * 4] = p;
        }
    }
    __syncthreads();   // the only barrier before the epilogue

    float score_part[16];
#pragma unroll
    for (int i = 0; i < 16; ++i) score_part[i] = 0.f;

    for (int ni = 0; ni < 2; ++ni) {
        const int colbase = (ni * 8 + wave) * 64;
        const int nt0     = colbase >> 4;

        floatx4 acc[4][4];
#pragma unroll
        for (int i = 0; i < 4; ++i)
#pragma unroll
            for (int j = 0; j < 4; ++j)
                acc[i][j] = (floatx4){0.f, 0.f, 0.f, 0.f};

#pragma unroll 2
        for (int kt = 0; kt < 32; ++kt) {
            short8 afr[4], bfr[4];
#pragma unroll
            for (int rg = 0; rg < 4; ++rg) {
                const unsigned short* ap = &sh.A[(rg * 16 + llo) * LDA + kt * 32 + lhi * 8];
                afr[rg] = *(const short8*)ap;
            }
#pragma unroll
            for (int j = 0; j < 4; ++j) {
                uint4 u = vp[((nt0 + j) * 32 + kt) * 64 + lane];
                bfr[j] = __builtin_bit_cast(short8, u);
            }
#pragma unroll
            for (int rg = 0; rg < 4; ++rg)
#pragma unroll
                for (int j = 0; j < 4; ++j)
                    acc[rg][j] = __builtin_amdgcn_mfma_f32_16x16x32_bf16(
                        afr[rg], bfr[j], acc[rg][j], 0, 0, 0);
        }

        // Epilogue: score_part[rg*4+r] += tanh(acc + dbias[c]) * w[c]
#pragma unroll
        for (int j = 0; j < 4; ++j) {
            const int c  = colbase + j * 16 + llo;
            const float db = dbp[(size_t)(b * 4 + 0) * Cn + c]
                           + dbp[(size_t)(b * 4 + 1) * Cn + c]
                           + dbp[(size_t)(b * 4 + 2) * Cn + c]
                           + dbp[(size_t)(b * 4 + 3) * Cn + c];
            const float wc = wv[c];
#pragma unroll
            for (int rg = 0; rg < 4; ++rg) {
#pragma unroll
                for (int r = 0; r < 4; ++r) {
                    float x = acc[rg][j][r] + db;
                    x = fminf(fmaxf(x, -12.f), 12.f);
                    float e = __expf(2.f * x);
                    float t = 1.f - 2.f / (e + 1.f);
                    score_part[rg * 4 + r] += t * wc;
                }
            }
        }
    }

    // Reduce over the 16 lanes (llo) that share each row.
#pragma unroll
    for (int i = 0; i < 16; ++i) {
        float v = score_part[i];
        v += __shfl_xor(v, 1);
        v += __shfl_xor(v, 2);
        v += __shfl_xor(v, 4);
        v += __shfl_xor(v, 8);
        score_part[i] = v;
    }
    if (llo == 0) {
#pragma unroll
        for (int rg = 0; rg < 4; ++rg)
#pragma unroll
            for (int r = 0; r < 4; ++r)
                atomicAdd(&sh.scores[rg * 16 + lhi * 4 + r], score_part[rg * 4 + r]);
    }
    __syncthreads();
    if (tid < BLK_M) scores_g[row0 + tid] = sh.scores[tid];
}

// Softmax over T per batch. grid 32 x 256.
__global__ void k_softmax(const float* __restrict__ scores, float* __restrict__ align) {
    const int b   = blockIdx.x;
    const int tid = threadIdx.x;
    const float* s = scores + b * Tn;
    float v[8];
    float lmax = -1e30f;
#pragma unroll
    for (int i = 0; i < 8; ++i) { v[i] = s[tid + i * 256]; lmax = fmaxf(lmax, v[i]); }
    for (int off = 1; off < 64; off <<= 1) lmax = fmaxf(lmax, __shfl_xor(lmax, off));
    __shared__ float red[4];
    __shared__ float red2[4];
    if ((tid & 63) == 0) red[tid >> 6] = lmax;
    __syncthreads();
    lmax = fmaxf(fmaxf(red[0], red[1]), fmaxf(red[2], red[3]));
    float lsum = 0.f;
#pragma unroll
    for (int i = 0; i < 8; ++i) { v[i] = __expf(v[i] - lmax); lsum += v[i]; }
    for (int off = 1; off < 64; off <<= 1) lsum += __shfl_xor(lsum, off);
    if ((tid & 63) == 0) red2[tid >> 6] = lsum;
    __syncthreads();
    lsum = red2[0] + red2[1] + red2[2] + red2[3];
    const float inv = 1.f / lsum;
#pragma unroll
    for (int i = 0; i < 8; ++i) align[b * Tn + tid + i * 256] = v[i] * inv;
}

// context stage 1: part[b][tc][h] = sum_{t in chunk} align[b][t] * enc[b][t][h]
// grid (32, 8) x 256 threads = 256 blocks (1/CU). Plain stores, no atomics.
__global__ void k_ctx1(const float* __restrict__ enc, const float* __restrict__ align,
                       float* __restrict__ part) {
    const int b   = blockIdx.x;
    const int tc  = blockIdx.y;
    const int tid = threadIdx.x;
    const float4* ep = (const float4*)(enc + ((size_t)b * Tn + tc * 256) * Hn);
    const float*  al = align + b * Tn + tc * 256;
    float4 acc = {0.f, 0.f, 0.f, 0.f};
#pragma unroll 4
    for (int t = 0; t < 256; ++t) {
        const float a = al[t];
        const float4 e = ep[t * 256 + tid];
        acc.x += a * e.x; acc.y += a * e.y; acc.z += a * e.z; acc.w += a * e.w;
    }
    ((float4*)part)[(b * 8 + tc) * 256 + tid] = acc;
}

// context stage 2: out[b][h] = sum_tc part[b][tc][h]. grid 32 x 256.
__global__ void k_ctx2(const float* __restrict__ part, float* __restrict__ out) {
    const int b   = blockIdx.x;
    const int tid = threadIdx.x;
    const float4* pp = (const float4*)part;
    float4 s = {0.f, 0.f, 0.f, 0.f};
#pragma unroll
    for (int tc = 0; tc < 8; ++tc) {
        float4 p = pp[(b * 8 + tc) * 256 + tid];
        s.x += p.x; s.y += p.y; s.z += p.z; s.w += p.w;
    }
    ((float4*)out)[b * 256 + tid] = s;
}

extern "C" void kernel_launch(void* const* d_in, const int* in_sizes, int n_in,
                              void* d_out, int out_size, void* d_ws, size_t ws_size,
                              hipStream_t stream) {
    const float* dec  = (const float*)d_in[0];   // [32,1,1024]
    const float* enc  = (const float*)d_in[1];   // [32,2048,1024]
    const float* W    = (const float*)d_in[2];   // [1024,1024]
    const float* V    = (const float*)d_in[3];   // [1024,1024]
    const float* bias = (const float*)d_in[4];   // [1024]
    const float* wv   = (const float*)d_in[5];   // [1024,1]
    float* out = (float*)d_out;                  // [32,1024]

    char* ws = (char*)d_ws;
    float* dbp    = (float*)(ws);                              // 32*4*1024*4 = 512 KB
    uint4* vpack  = (uint4*)(ws + 524288);                     // 2 MB
    float* scores = (float*)(ws + 524288 + 2097152);           // 256 KB
    float* align  = (float*)(ws + 524288 + 2097152 + 262144);  // 256 KB
    float* cpart  = (float*)(ws + 524288 + 2097152 + 262144 + 262144); // 1 MB

    k_dbias  <<<dim3(32, 4, 4), 256, 0, stream>>>(dec, W, bias, dbp);
    k_vpack  <<<2048, 64, 0, stream>>>(V, vpack);
    k_scores <<<1024, 512, 0, stream>>>(enc, vpack, dbp, wv, scores);
    k_softmax<<<32, 256, 0, stream>>>(scores, align);
    k_ctx1   <<<dim3(32, 8), 256, 0, stream>>>(enc, align, cpart);
    k_ctx2   <<<32, 256, 0, stream>>>(cpart, out);
}